// Round 1
// baseline (772.080 us; speedup 1.0000x reference)
//
#include <hip/hip_runtime.h>

#define NEGF (-1e30f)

constexpr int B = 64, T = 2048, V = 256, L = 256;
constexpr int S = 2 * L + 1;  // 513
constexpr int PF = 4;         // prefetch depth (time steps ahead)

// log(exp(a)+exp(b)+exp(c)), safe for NEGF sentinels
__device__ __forceinline__ float lae3(float a, float b, float c) {
  float m = fmaxf(fmaxf(a, b), c);  // v_max3_f32
  float s = __expf(a - m) + __expf(b - m) + __expf(c - m);
  return m + __logf(s);
}
__device__ __forceinline__ float lae2(float a, float b) {
  float m = fmaxf(a, b);
  float s = __expf(a - m) + __expf(b - m);
  return m + __logf(s);
}

// Kernel 1: lse[b,t] = logsumexp over V=256 of logits[b,t,:]. One wave per row.
__global__ __launch_bounds__(256) void lse_kernel(const float* __restrict__ logits,
                                                  float* __restrict__ lse, int nrows) {
  int gw = (blockIdx.x * 256 + threadIdx.x) >> 6;  // global wave id = row
  int lane = threadIdx.x & 63;
  if (gw >= nrows) return;
  float4 v = reinterpret_cast<const float4*>(logits)[(size_t)gw * 64 + lane];
  float m = fmaxf(fmaxf(v.x, v.y), fmaxf(v.z, v.w));
#pragma unroll
  for (int off = 32; off; off >>= 1) m = fmaxf(m, __shfl_xor(m, off));
  float s = __expf(v.x - m) + __expf(v.y - m) + __expf(v.z - m) + __expf(v.w - m);
#pragma unroll
  for (int off = 32; off; off >>= 1) s += __shfl_xor(s, off);
  if (lane == 0) lse[gw] = m + __logf(s);
}

// Kernel 2: CTC alpha recursion. One block per batch element.
// Thread tid owns state s=tid (0..511); thread 0 additionally owns s=512.
// Double-buffered alpha in LDS -> ONE barrier per time step.
__global__ __launch_bounds__(512) void ctc_kernel(const float* __restrict__ logits,
                                                  const int* __restrict__ labels,
                                                  const int* __restrict__ ilens,
                                                  const float* __restrict__ lse,
                                                  float* __restrict__ per_loss) {
  const int b = blockIdx.x;
  const int tid = threadIdx.x;
  __shared__ float s_alpha[2][S + 2];  // [s+2]; slots 0,1 = NEGF (s=-2,-1)
  __shared__ int s_ext[S];
  __shared__ int s_cnt;

  if (tid == 0) s_cnt = 0;
  for (int s = tid; s < S; s += 512) s_ext[s] = 0;
  if (tid < 2) { s_alpha[0][tid] = NEGF; s_alpha[1][tid] = NEGF; }
  __syncthreads();
  if (tid < L) {
    int lab = labels[b * L + tid];
    int ok = (lab >= 0) ? 1 : 0;
    if (!ok) lab = 0;
    s_ext[2 * tid + 1] = lab;
    atomicAdd(&s_cnt, ok);
  }
  __syncthreads();
  const int tlen = s_cnt;
  const int ilen = ilens[b];
  const int s0 = tid;
  const int ext0 = s_ext[s0];
  const bool skip0 = (s0 >= 2) && (ext0 != 0) && (ext0 != s_ext[s0 - 2]);
  const bool valid0 = s0 < 2 * tlen + 1;
  const bool valid_top = (S - 1) < 2 * tlen + 1;  // only if tlen==L

  const float* lgb = logits + (size_t)b * T * V;
  const float* lseb = lse + (size_t)b * T;

  // t = 0 init
  float e0 = lgb[ext0] - lseb[0];
  float a_own = (s0 < 2 && valid0) ? e0 : NEGF;
  s_alpha[0][s0 + 2] = a_own;
  float a_top = NEGF;  // state S-1=512 (blank), owned by thread 0
  if (tid == 0) s_alpha[0][S + 1] = NEGF;

  // register prefetch: rows t=1..PF
  float eBuf[PF], lBuf[PF];
#pragma unroll
  for (int d = 0; d < PF; ++d) {
    int t = 1 + d;
    eBuf[d] = lgb[t * V + ext0];
    lBuf[d] = lseb[t];
  }
  int cur = 0;
  __syncthreads();

#define STEP(p, t_)                                             \
  {                                                             \
    const int t = (t_);                                         \
    float e = eBuf[p] - lBuf[p];                                \
    int tn = t + PF;                                            \
    if (tn > T - 1) tn = T - 1;                                 \
    eBuf[p] = lgb[tn * V + ext0];                               \
    lBuf[p] = lseb[tn];                                         \
    float p1 = s_alpha[cur][s0 + 1];                            \
    float p2 = s_alpha[cur][s0];                                \
    float p2m = skip0 ? p2 : NEGF;                              \
    float na = lae3(a_own, p1, p2m) + e;                        \
    na = valid0 ? na : NEGF;                                    \
    na = (t < ilen) ? na : a_own;                               \
    s_alpha[cur ^ 1][s0 + 2] = na;                              \
    a_own = na;                                                 \
    if (tid == 0) {                                             \
      float q1 = s_alpha[cur][(S - 1) + 1];                     \
      float nt = lae2(a_top, q1) + e; /* blank: no skip */      \
      nt = valid_top ? nt : NEGF;                               \
      nt = (t < ilen) ? nt : a_top;                             \
      s_alpha[cur ^ 1][(S - 1) + 2] = nt;                       \
      a_top = nt;                                               \
    }                                                           \
    __syncthreads();                                            \
    cur ^= 1;                                                   \
  }

  // main loop: t = 1 .. 2044 in groups of 4 (static prefetch phases)
  for (int tb = 1; tb <= T - PF; tb += PF) {
    STEP(0, tb)
    STEP(1, tb + 1)
    STEP(2, tb + 2)
    STEP(3, tb + 3)
  }
  // tail: t = 2045, 2046, 2047 (phases 0,1,2)
  STEP(0, T - 3)
  STEP(1, T - 2)
  STEP(2, T - 1)
#undef STEP

  if (tid == 0) {
    float af1 = s_alpha[cur][2 * tlen + 2];      // s = 2*tlen
    float af2 = s_alpha[cur][2 * tlen + 1];      // s = 2*tlen - 1
    float ll = lae2(af1, af2);
    float per = (ll > NEGF * 0.5f) ? (-ll / (float)tlen) : 0.0f;
    per_loss[b] = per;
  }
}

// Kernel 3: mean over B=64 per-sample losses
__global__ void final_kernel(const float* __restrict__ per, float* __restrict__ out) {
  float v = per[threadIdx.x];
#pragma unroll
  for (int off = 32; off; off >>= 1) v += __shfl_xor(v, off);
  if (threadIdx.x == 0) out[0] = v * (1.0f / (float)B);
}

extern "C" void kernel_launch(void* const* d_in, const int* in_sizes, int n_in,
                              void* d_out, int out_size, void* d_ws, size_t ws_size,
                              hipStream_t stream) {
  const float* logits = (const float*)d_in[0];
  const int* labels = (const int*)d_in[1];
  const int* ilens = (const int*)d_in[2];
  float* out = (float*)d_out;
  float* lse = (float*)d_ws;                  // B*T floats
  float* per = lse + (size_t)B * T;           // B floats
  const int nrows = B * T;
  lse_kernel<<<nrows / 4, 256, 0, stream>>>(logits, lse, nrows);
  ctc_kernel<<<B, 512, 0, stream>>>(logits, labels, ilens, lse, per);
  final_kernel<<<1, 64, 0, stream>>>(per, out);
}